// Round 2
// baseline (4506.604 us; speedup 1.0000x reference)
//
#include <hip/hip_runtime.h>
#include <hip/hip_bf16.h>
#include <math.h>

#define HIDDEN 2560
#define NH 32
#define NKV 8
#define HD 80
#define BATCH 2
#define SEQ 2048
#define QH_COLS (NH*HD)    // 2560
#define KV_COLS (NKV*HD)   // 640
#define ROWS (BATCH*SEQ)   // 4096

typedef __attribute__((ext_vector_type(4))) float floatx4;
typedef __attribute__((ext_vector_type(8))) short shortx8;   // bf16x8 MFMA frag

// ---------------- fp32 tiled GEMM, templated output ----------------
#define BM 64
#define BN 64
#define BK 16

__device__ inline void storeC(float v, float* p) { *p = v; }
__device__ inline void storeC(float v, __hip_bfloat16* p) { *p = __float2bfloat16(v); }

template <typename OutT>
__global__ __launch_bounds__(256) void sgemm_t(const float* __restrict__ A,
                                               const float* __restrict__ B,
                                               OutT* __restrict__ C,
                                               int M, int N, int K) {
    __shared__ float As[BK][BM + 4];
    __shared__ float Bs[BK][BN + 4];
    const int tid = threadIdx.x;
    const int bm = blockIdx.y * BM;
    const int bn = blockIdx.x * BN;
    const int tx = tid & 15;
    const int ty = tid >> 4;
    float acc[4][4];
#pragma unroll
    for (int i = 0; i < 4; i++)
#pragma unroll
        for (int j = 0; j < 4; j++) acc[i][j] = 0.0f;

    for (int k0 = 0; k0 < K; k0 += BK) {
#pragma unroll
        for (int i = 0; i < 4; i++) {
            int r = (tid >> 4) + i * 16;
            int c = tid & 15;
            As[c][r] = A[(size_t)(bm + r) * K + (k0 + c)];
        }
#pragma unroll
        for (int i = 0; i < 4; i++) {
            int r = (tid >> 6) + i * 4;
            int c = tid & 63;
            Bs[r][c] = B[(size_t)(k0 + r) * N + (bn + c)];
        }
        __syncthreads();
#pragma unroll
        for (int kk = 0; kk < BK; kk++) {
            float a[4], b[4];
#pragma unroll
            for (int i = 0; i < 4; i++) a[i] = As[kk][ty * 4 + i];
#pragma unroll
            for (int j = 0; j < 4; j++) b[j] = Bs[kk][tx * 4 + j];
#pragma unroll
            for (int i = 0; i < 4; i++)
#pragma unroll
                for (int j = 0; j < 4; j++) acc[i][j] += a[i] * b[j];
        }
        __syncthreads();
    }
#pragma unroll
    for (int i = 0; i < 4; i++)
#pragma unroll
        for (int j = 0; j < 4; j++)
            storeC(acc[i][j], &C[(size_t)(bm + ty * 4 + i) * N + (bn + tx * 4 + j)]);
}

// ---------------- RoPE, in place on bf16 q/k ----------------
__global__ __launch_bounds__(256) void rope_bf16(__hip_bfloat16* __restrict__ qh,
                                                 __hip_bfloat16* __restrict__ kh,
                                                 const float* __restrict__ cf,
                                                 const float* __restrict__ sf) {
    int idx = blockIdx.x * 256 + threadIdx.x;   // ROWS*40*40 threads
    int d  = idx % 40;
    int t  = idx / 40;
    int hh = t % (NH + NKV);
    int g  = t / (NH + NKV);
    int s  = g & (SEQ - 1);
    float c1 = cf[s * HD + d],      s1 = sf[s * HD + d];
    float c2 = cf[s * HD + d + 40], s2 = sf[s * HD + d + 40];
    __hip_bfloat16* p = (hh < NH) ? (qh + (size_t)g * QH_COLS + hh * HD)
                                  : (kh + (size_t)g * KV_COLS + (hh - NH) * HD);
    float x1 = __bfloat162float(p[d]);
    float x2 = __bfloat162float(p[d + 40]);
    p[d]      = __float2bfloat16(x1 * c1 - x2 * s1);
    p[d + 40] = __float2bfloat16(x2 * c2 + x1 * s2);
}

// ---------------- MFMA flash attention ----------------
// grid (SEQ/64, NH, BATCH), block 256 = 4 waves. Wave w owns Q rows w*16..w*16+15
// of the block's 64-row Q tile. K/V tiles of 64, staged in LDS.
// MFMA 16x16x32 bf16 layouts (HW-verified, learn_hip m89/m91/m120):
//   C/D: col = lane&15, row = (lane>>4)*4 + reg
//   A:   A[m = lane&15][k = (lane>>4)*8 + j], j=0..7
//   B:   B[k = (lane>>4)*8 + j][n = lane&15]
#define QS_STRIDE 104   // bf16 units; 208B rows, 16B-aligned
#define VT_STRIDE 72    // 144B rows
#define PW_STRIDE 72

__global__ __launch_bounds__(256) void attn_mfma(const __hip_bfloat16* __restrict__ qh,
                                                 const __hip_bfloat16* __restrict__ kh,
                                                 const __hip_bfloat16* __restrict__ vh,
                                                 float* __restrict__ ob) {
    __shared__ __align__(16) unsigned short Qs[64 * QS_STRIDE];  // [r][k], k 80..95 zero
    __shared__ __align__(16) unsigned short Ks[64 * QS_STRIDE];  // [kv_row][k], k 80..95 zero
    __shared__ __align__(16) unsigned short Vt[80 * VT_STRIDE];  // [d][kv_row]
    __shared__ __align__(16) unsigned short Pw[4][16 * PW_STRIDE]; // per-wave P, [q][kv_row]

    const int tid  = threadIdx.x;
    const int wave = tid >> 6;
    const int lane = tid & 63;
    const int m16  = lane & 15;
    const int quad = lane >> 4;
    const int qt = blockIdx.x;
    const int h  = blockIdx.y;
    const int b  = blockIdx.z;
    const int kvh = h >> 2;
    const float scale = 0.11180339887498949f;   // 1/sqrt(80)
    const int qbase = qt * 64;
    const unsigned short* qg = (const unsigned short*)qh;
    const unsigned short* kg = (const unsigned short*)kh;
    const unsigned short* vg = (const unsigned short*)vh;

    // stage Q tile (64 x 96, cols 80..95 zeroed)
    {
        const size_t grow = (size_t)(b * SEQ + qbase);
#pragma unroll
        for (int i = 0; i < 24; i++) {
            int e = i * 256 + tid;
            int r = e / 96, c = e % 96;
            unsigned short v = 0;
            if (c < 80) v = qg[(grow + r) * QH_COLS + h * HD + c];
            Qs[r * QS_STRIDE + c] = v;
        }
    }
    __syncthreads();
    // Q A-frags: rows wave*16+m16, k = f*32 + quad*8 + j
    shortx8 qfrag[3];
    {
        const unsigned short* qrow = &Qs[(wave * 16 + m16) * QS_STRIDE + quad * 8];
#pragma unroll
        for (int f = 0; f < 3; f++)
            qfrag[f] = *(const shortx8*)(qrow + f * 32);
    }

    floatx4 Oacc[5];
#pragma unroll
    for (int n = 0; n < 5; n++) Oacc[n] = (floatx4){0.f, 0.f, 0.f, 0.f};
    float mrow[4], lrow[4];
#pragma unroll
    for (int p = 0; p < 4; p++) { mrow[p] = -1.0e30f; lrow[p] = 0.0f; }

    for (int kt = 0; kt <= qt; kt++) {
        __syncthreads();   // protect Ks/Vt from previous iteration's readers
        const size_t krow = (size_t)(b * SEQ + kt * 64);
#pragma unroll
        for (int i = 0; i < 24; i++) {   // K tile 64 x 96
            int e = i * 256 + tid;
            int r = e / 96, c = e % 96;
            unsigned short v = 0;
            if (c < 80) v = kg[(krow + r) * KV_COLS + kvh * HD + c];
            Ks[r * QS_STRIDE + c] = v;
        }
#pragma unroll
        for (int i = 0; i < 20; i++) {   // V tile transposed: Vt[d][kv_row]
            int e = i * 256 + tid;       // 64*80
            int r = e / 80, c = e % 80;
            Vt[c * VT_STRIDE + r] = vg[(krow + r) * KV_COLS + kvh * HD + c];
        }
        __syncthreads();

        const bool diag = (kt == qt);
        const int gmax = diag ? wave : 3;   // col-groups g>wave fully masked on diagonal

        // S = Q K^T  (fp32 C-layout frags)
        floatx4 S[4];
#pragma unroll
        for (int g = 0; g < 4; g++) {
            if (g > gmax) continue;
            floatx4 s = (floatx4){0.f, 0.f, 0.f, 0.f};
            const unsigned short* krow_l = &Ks[(g * 16 + m16) * QS_STRIDE + quad * 8];
#pragma unroll
            for (int f = 0; f < 3; f++) {
                shortx8 kf = *(const shortx8*)(krow_l + f * 32);
                s = __builtin_amdgcn_mfma_f32_16x16x32_bf16(qfrag[f], kf, s, 0, 0, 0);
            }
            S[g] = s;
        }

        // scale + causal mask + online softmax
        float newm[4];
#pragma unroll
        for (int p = 0; p < 4; p++) newm[p] = mrow[p];
#pragma unroll
        for (int g = 0; g < 4; g++) {
            if (g > gmax) continue;
#pragma unroll
            for (int p = 0; p < 4; p++) {
                float s = S[g][p] * scale;
                if (diag && g == wave && (g * 16 + m16) > (wave * 16 + quad * 4 + p))
                    s = -1.0e30f;
                S[g][p] = s;
                newm[p] = fmaxf(newm[p], s);
            }
        }
#pragma unroll
        for (int p = 0; p < 4; p++)
#pragma unroll
            for (int o = 1; o < 16; o <<= 1)
                newm[p] = fmaxf(newm[p], __shfl_xor(newm[p], o));

        float alpha[4], rsum[4];
#pragma unroll
        for (int p = 0; p < 4; p++) {
            alpha[p] = __expf(mrow[p] - newm[p]);
            rsum[p] = 0.0f;
        }
#pragma unroll
        for (int g = 0; g < 4; g++) {
#pragma unroll
            for (int p = 0; p < 4; p++) {
                unsigned short pb = 0;
                if (g <= gmax) {
                    float pe = __expf(S[g][p] - newm[p]);
                    rsum[p] += pe;
                    __hip_bfloat16 hb = __float2bfloat16(pe);
                    pb = *(unsigned short*)&hb;
                }
                Pw[wave][(quad * 4 + p) * PW_STRIDE + g * 16 + m16] = pb;
            }
        }
#pragma unroll
        for (int p = 0; p < 4; p++) {
#pragma unroll
            for (int o = 1; o < 16; o <<= 1)
                rsum[p] += __shfl_xor(rsum[p], o);
            lrow[p] = lrow[p] * alpha[p] + rsum[p];
            mrow[p] = newm[p];
        }
#pragma unroll
        for (int n = 0; n < 5; n++)
#pragma unroll
            for (int p = 0; p < 4; p++) Oacc[n][p] *= alpha[p];

        // O += P V  (P via LDS roundtrip C-layout -> A-layout; wave-local, no barrier)
        shortx8 pfrag[2];
#pragma unroll
        for (int f = 0; f < 2; f++)
            pfrag[f] = *(const shortx8*)(&Pw[wave][m16 * PW_STRIDE + f * 32 + quad * 8]);
#pragma unroll
        for (int n = 0; n < 5; n++) {
#pragma unroll
            for (int f = 0; f < 2; f++) {
                shortx8 vf = *(const shortx8*)(&Vt[(n * 16 + m16) * VT_STRIDE + f * 32 + quad * 8]);
                Oacc[n] = __builtin_amdgcn_mfma_f32_16x16x32_bf16(pfrag[f], vf, Oacc[n], 0, 0, 0);
            }
        }
    }

    // epilogue: divide by l, store fp32
    float inv[4];
#pragma unroll
    for (int p = 0; p < 4; p++) inv[p] = 1.0f / lrow[p];
#pragma unroll
    for (int n = 0; n < 5; n++)
#pragma unroll
        for (int p = 0; p < 4; p++) {
            size_t row = (size_t)(b * SEQ + qbase + wave * 16 + quad * 4 + p);
            ob[row * QH_COLS + h * HD + n * 16 + m16] = Oacc[n][p] * inv[p];
        }
}

// ---------------- launch ----------------
extern "C" void kernel_launch(void* const* d_in, const int* in_sizes, int n_in,
                              void* d_out, int out_size, void* d_ws, size_t ws_size,
                              hipStream_t stream) {
    const float* x    = (const float*)d_in[0];
    const float* cf   = (const float*)d_in[1];
    const float* sf   = (const float*)d_in[2];
    const float* Wq   = (const float*)d_in[3];
    const float* Wk   = (const float*)d_in[4];
    const float* Wv   = (const float*)d_in[5];
    const float* Wo   = (const float*)d_in[6];
    float* out = (float*)d_out;

    __hip_bfloat16* qh = (__hip_bfloat16*)d_ws;            // 4096 x 2560 bf16
    __hip_bfloat16* kh = qh + (size_t)ROWS * QH_COLS;      // 4096 x 640
    __hip_bfloat16* vh = kh + (size_t)ROWS * KV_COLS;      // 4096 x 640
    float* ob = (float*)(vh + (size_t)ROWS * KV_COLS);     // 4096 x 2560 fp32

    dim3 blk(256);
    sgemm_t<__hip_bfloat16><<<dim3(QH_COLS / BN, ROWS / BM), blk, 0, stream>>>(x, Wq, qh, ROWS, QH_COLS, HIDDEN);
    sgemm_t<__hip_bfloat16><<<dim3(KV_COLS / BN, ROWS / BM), blk, 0, stream>>>(x, Wk, kh, ROWS, KV_COLS, HIDDEN);
    sgemm_t<__hip_bfloat16><<<dim3(KV_COLS / BN, ROWS / BM), blk, 0, stream>>>(x, Wv, vh, ROWS, KV_COLS, HIDDEN);
    rope_bf16<<<(ROWS * (NH + NKV) * 40) / 256, blk, 0, stream>>>(qh, kh, cf, sf);
    attn_mfma<<<dim3(SEQ / 64, NH, BATCH), blk, 0, stream>>>(qh, kh, vh, ob);
    sgemm_t<float><<<dim3(HIDDEN / BN, ROWS / BM), blk, 0, stream>>>(ob, Wo, out, ROWS, HIDDEN, HIDDEN);
}

// Round 3
// 2357.906 us; speedup vs baseline: 1.9113x; 1.9113x over previous
//
#include <hip/hip_runtime.h>
#include <hip/hip_bf16.h>
#include <math.h>

#define HIDDEN 2560
#define NH 32
#define NKV 8
#define HD 80
#define BATCH 2
#define SEQ 2048
#define QH_COLS (NH*HD)    // 2560
#define KV_COLS (NKV*HD)   // 640
#define ROWS (BATCH*SEQ)   // 4096

typedef __attribute__((ext_vector_type(4))) float floatx4;
typedef __attribute__((ext_vector_type(8))) short shortx8;   // bf16x8 MFMA frag

// ---------------- fp32 tiled GEMM, templated output ----------------
#define BM 64
#define BN 64
#define BK 16

__device__ inline void storeC(float v, float* p) { *p = v; }
__device__ inline void storeC(float v, __hip_bfloat16* p) { *p = __float2bfloat16(v); }

template <typename OutT>
__global__ __launch_bounds__(256) void sgemm_t(const float* __restrict__ A,
                                               const float* __restrict__ B,
                                               OutT* __restrict__ C,
                                               int M, int N, int K) {
    __shared__ float As[BK][BM + 4];
    __shared__ float Bs[BK][BN + 4];
    const int tid = threadIdx.x;
    const int bm = blockIdx.y * BM;
    const int bn = blockIdx.x * BN;
    const int tx = tid & 15;
    const int ty = tid >> 4;
    float acc[4][4];
#pragma unroll
    for (int i = 0; i < 4; i++)
#pragma unroll
        for (int j = 0; j < 4; j++) acc[i][j] = 0.0f;

    for (int k0 = 0; k0 < K; k0 += BK) {
#pragma unroll
        for (int i = 0; i < 4; i++) {
            int r = (tid >> 4) + i * 16;
            int c = tid & 15;
            As[c][r] = A[(size_t)(bm + r) * K + (k0 + c)];
        }
#pragma unroll
        for (int i = 0; i < 4; i++) {
            int r = (tid >> 6) + i * 4;
            int c = tid & 63;
            Bs[r][c] = B[(size_t)(k0 + r) * N + (bn + c)];
        }
        __syncthreads();
#pragma unroll
        for (int kk = 0; kk < BK; kk++) {
            float a[4], b[4];
#pragma unroll
            for (int i = 0; i < 4; i++) a[i] = As[kk][ty * 4 + i];
#pragma unroll
            for (int j = 0; j < 4; j++) b[j] = Bs[kk][tx * 4 + j];
#pragma unroll
            for (int i = 0; i < 4; i++)
#pragma unroll
                for (int j = 0; j < 4; j++) acc[i][j] += a[i] * b[j];
        }
        __syncthreads();
    }
#pragma unroll
    for (int i = 0; i < 4; i++)
#pragma unroll
        for (int j = 0; j < 4; j++)
            storeC(acc[i][j], &C[(size_t)(bm + ty * 4 + i) * N + (bn + tx * 4 + j)]);
}

// ---------------- RoPE, in place on bf16 q/k ----------------
__global__ __launch_bounds__(256) void rope_bf16(__hip_bfloat16* __restrict__ qh,
                                                 __hip_bfloat16* __restrict__ kh,
                                                 const float* __restrict__ cf,
                                                 const float* __restrict__ sf) {
    int idx = blockIdx.x * 256 + threadIdx.x;
    int d  = idx % 40;
    int t  = idx / 40;
    int hh = t % (NH + NKV);
    int g  = t / (NH + NKV);
    int s  = g & (SEQ - 1);
    float c1 = cf[s * HD + d],      s1 = sf[s * HD + d];
    float c2 = cf[s * HD + d + 40], s2 = sf[s * HD + d + 40];
    __hip_bfloat16* p = (hh < NH) ? (qh + (size_t)g * QH_COLS + hh * HD)
                                  : (kh + (size_t)g * KV_COLS + (hh - NH) * HD);
    float x1 = __bfloat162float(p[d]);
    float x2 = __bfloat162float(p[d + 40]);
    p[d]      = __float2bfloat16(x1 * c1 - x2 * s1);
    p[d + 40] = __float2bfloat16(x2 * c2 + x1 * s2);
}

// ---------------- MFMA flash attention, async-staged ----------------
// grid (SEQ/64, NH, BATCH), block 256 = 4 waves. Wave w owns Q rows w*16..w*16+15.
// Q/K tiles: 64 rows x 80 bf16, UNPADDED 160B rows (10 x 1KB chunks) so
// global_load_lds width=16 can stage them. K double-buffered; prefetch of tile
// kt+1 issued before compute of kt -> vmcnt drain at the end-of-compute barrier.
// V: 16B vector reg loads issued with the prefetch, written transposed to Vt
// (stride 72) after the compute barrier.
#define VT_S 72
#define PW_S 72

// stage one 64x80 bf16 tile (row stride rs elements) into lds via async 16B chunks
__device__ __forceinline__ void async_tile(const unsigned short* gbase, size_t rs,
                                           unsigned short* lds, int wave, int lane) {
    for (int c = wave; c < 10; c += 4) {
        int o = c * 1024 + lane * 16;     // byte offset within the packed 10240B tile
        int r = o / 160;
        int cb = o % 160;
        const unsigned short* g = gbase + (size_t)r * rs + (cb >> 1);
        __builtin_amdgcn_global_load_lds(
            (const __attribute__((address_space(1))) unsigned int*)g,
            (__attribute__((address_space(3))) unsigned int*)(lds + c * 512 + lane * 8),
            16, 0, 0);
    }
}

__global__ __launch_bounds__(256) void attn_mfma(const __hip_bfloat16* __restrict__ qh,
                                                 const __hip_bfloat16* __restrict__ kh,
                                                 const __hip_bfloat16* __restrict__ vh,
                                                 float* __restrict__ ob) {
    __shared__ __align__(16) unsigned short Qs[64 * 80];
    __shared__ __align__(16) unsigned short Kb[2][64 * 80];
    __shared__ __align__(16) unsigned short Vt[80 * VT_S];
    __shared__ __align__(16) unsigned short Pw[4][16 * PW_S];

    const int tid  = threadIdx.x;
    const int wave = tid >> 6;
    const int lane = tid & 63;
    const int m16  = lane & 15;
    const int quad = lane >> 4;
    const int qt = blockIdx.x;
    const int h  = blockIdx.y;
    const int b  = blockIdx.z;
    const int kvh = h >> 2;
    const float scale = 0.11180339887498949f;   // 1/sqrt(80)
    const int qbase = qt * 64;

    const unsigned short* qg = (const unsigned short*)qh + (size_t)(b * SEQ + qbase) * QH_COLS + h * HD;
    const unsigned short* kg0 = (const unsigned short*)kh + (size_t)(b * SEQ) * KV_COLS + kvh * HD;
    const unsigned short* vg0 = (const unsigned short*)vh + (size_t)(b * SEQ) * KV_COLS + kvh * HD;

    // ---- prologue: async-stage Q and K0; reg-load V0 ----
    async_tile(qg, QH_COLS, Qs, wave, lane);
    async_tile(kg0, KV_COLS, Kb[0], wave, lane);
    shortx8 vr[3];
    {
        const unsigned short* vg = vg0;
#pragma unroll
        for (int j = 0; j < 3; j++) {
            int c = j * 256 + tid;
            if (c < 640) {
                int dblk = c >> 6, r = c & 63;
                vr[j] = *(const shortx8*)(vg + (size_t)r * KV_COLS + dblk * 8);
            }
        }
    }
    __syncthreads();    // Q, K0 in LDS; vr ready

    // Vt[d][kv] <- V0
#pragma unroll
    for (int j = 0; j < 3; j++) {
        int c = j * 256 + tid;
        if (c < 640) {
            int dblk = c >> 6, r = c & 63;
#pragma unroll
            for (int i = 0; i < 8; i++) Vt[(dblk * 8 + i) * VT_S + r] = vr[j][i];
        }
    }

    // Q A-frags from LDS (rows wave*16+m16), k = f*32 + quad*8 + j; k>=80 zeroed
    const shortx8 z8 = {0, 0, 0, 0, 0, 0, 0, 0};
    shortx8 qf0, qf1, qf2;
    {
        const unsigned short* qrow = &Qs[(wave * 16 + m16) * 80];
        qf0 = *(const shortx8*)(qrow + quad * 8);
        qf1 = *(const shortx8*)(qrow + 32 + quad * 8);
        shortx8 t = *(const shortx8*)(qrow + 64 + (quad & 1) * 8);
        qf2 = (quad < 2) ? t : z8;
    }
    __syncthreads();    // Vt ready

    floatx4 Oacc[5];
#pragma unroll
    for (int n = 0; n < 5; n++) Oacc[n] = (floatx4){0.f, 0.f, 0.f, 0.f};
    float mrow[4], lrow[4];
#pragma unroll
    for (int p = 0; p < 4; p++) { mrow[p] = -1.0e30f; lrow[p] = 0.0f; }

    for (int kt = 0; kt <= qt; kt++) {
        const int cur = kt & 1;
        const bool more = (kt < qt);
        // ---- prefetch tile kt+1 (fully async; drained by the post-compute barrier) ----
        if (more) {
            const unsigned short* kg = kg0 + (size_t)(kt + 1) * 64 * KV_COLS;
            async_tile(kg, KV_COLS, Kb[cur ^ 1], wave, lane);
            const unsigned short* vg = vg0 + (size_t)(kt + 1) * 64 * KV_COLS;
#pragma unroll
            for (int j = 0; j < 3; j++) {
                int c = j * 256 + tid;
                if (c < 640) {
                    int dblk = c >> 6, r = c & 63;
                    vr[j] = *(const shortx8*)(vg + (size_t)r * KV_COLS + dblk * 8);
                }
            }
        }

        // ---- compute on Kb[cur], Vt ----
        const bool diag = (kt == qt);
        const int gmax = diag ? wave : 3;

        floatx4 S[4];
#pragma unroll
        for (int g = 0; g < 4; g++) {
            if (g > gmax) continue;
            const unsigned short* krow = &Kb[cur][(g * 16 + m16) * 80];
            shortx8 kf0 = *(const shortx8*)(krow + quad * 8);
            shortx8 kf1 = *(const shortx8*)(krow + 32 + quad * 8);
            shortx8 t  = *(const shortx8*)(krow + 64 + (quad & 1) * 8);
            shortx8 kf2 = (quad < 2) ? t : z8;
            floatx4 s = (floatx4){0.f, 0.f, 0.f, 0.f};
            s = __builtin_amdgcn_mfma_f32_16x16x32_bf16(qf0, kf0, s, 0, 0, 0);
            s = __builtin_amdgcn_mfma_f32_16x16x32_bf16(qf1, kf1, s, 0, 0, 0);
            s = __builtin_amdgcn_mfma_f32_16x16x32_bf16(qf2, kf2, s, 0, 0, 0);
            S[g] = s;
        }

        // scale + causal mask + online softmax
        float newm[4];
#pragma unroll
        for (int p = 0; p < 4; p++) newm[p] = mrow[p];
#pragma unroll
        for (int g = 0; g < 4; g++) {
            if (g > gmax) continue;
#pragma unroll
            for (int p = 0; p < 4; p++) {
                float s = S[g][p] * scale;
                if (diag && g == wave && (g * 16 + m16) > (wave * 16 + quad * 4 + p))
                    s = -1.0e30f;
                S[g][p] = s;
                newm[p] = fmaxf(newm[p], s);
            }
        }
#pragma unroll
        for (int p = 0; p < 4; p++)
#pragma unroll
            for (int o = 1; o < 16; o <<= 1)
                newm[p] = fmaxf(newm[p], __shfl_xor(newm[p], o));

        float alpha[4], rsum[4];
#pragma unroll
        for (int p = 0; p < 4; p++) {
            alpha[p] = __expf(mrow[p] - newm[p]);
            rsum[p] = 0.0f;
        }
#pragma unroll
        for (int g = 0; g < 4; g++) {
#pragma unroll
            for (int p = 0; p < 4; p++) {
                unsigned short pb = 0;
                if (g <= gmax) {
                    float pe = __expf(S[g][p] - newm[p]);
                    rsum[p] += pe;
                    __hip_bfloat16 hb = __float2bfloat16(pe);
                    pb = *(unsigned short*)&hb;
                }
                Pw[wave][(quad * 4 + p) * PW_S + g * 16 + m16] = pb;
            }
        }
#pragma unroll
        for (int p = 0; p < 4; p++) {
#pragma unroll
            for (int o = 1; o < 16; o <<= 1)
                rsum[p] += __shfl_xor(rsum[p], o);
            lrow[p] = lrow[p] * alpha[p] + rsum[p];
            mrow[p] = newm[p];
        }
#pragma unroll
        for (int n = 0; n < 5; n++)
#pragma unroll
            for (int p = 0; p < 4; p++) Oacc[n][p] *= alpha[p];

        // O += P V   (P roundtrip is wave-local: no barrier needed)
        shortx8 pfrag[2];
#pragma unroll
        for (int f = 0; f < 2; f++)
            pfrag[f] = *(const shortx8*)(&Pw[wave][m16 * PW_S + f * 32 + quad * 8]);
#pragma unroll
        for (int n = 0; n < 5; n++) {
#pragma unroll
            for (int f = 0; f < 2; f++) {
                shortx8 vf = *(const shortx8*)(&Vt[(n * 16 + m16) * VT_S + f * 32 + quad * 8]);
                Oacc[n] = __builtin_amdgcn_mfma_f32_16x16x32_bf16(pfrag[f], vf, Oacc[n], 0, 0, 0);
            }
        }

        __syncthreads();   // everyone done with Vt/Kb[cur]; drains vmcnt -> Kb[cur^1] + vr ready
        if (more) {
#pragma unroll
            for (int j = 0; j < 3; j++) {
                int c = j * 256 + tid;
                if (c < 640) {
                    int dblk = c >> 6, r = c & 63;
#pragma unroll
                    for (int i = 0; i < 8; i++) Vt[(dblk * 8 + i) * VT_S + r] = vr[j][i];
                }
            }
        }
        __syncthreads();   // Vt(kt+1) visible
    }

    // epilogue
    float inv[4];
#pragma unroll
    for (int p = 0; p < 4; p++) inv[p] = 1.0f / lrow[p];
#pragma unroll
    for (int n = 0; n < 5; n++)
#pragma unroll
        for (int p = 0; p < 4; p++) {
            size_t row = (size_t)(b * SEQ + qbase + wave * 16 + quad * 4 + p);
            ob[row * QH_COLS + h * HD + n * 16 + m16] = Oacc[n][p] * inv[p];
        }
}

// ---------------- launch ----------------
extern "C" void kernel_launch(void* const* d_in, const int* in_sizes, int n_in,
                              void* d_out, int out_size, void* d_ws, size_t ws_size,
                              hipStream_t stream) {
    const float* x    = (const float*)d_in[0];
    const float* cf   = (const float*)d_in[1];
    const float* sf   = (const float*)d_in[2];
    const float* Wq   = (const float*)d_in[3];
    const float* Wk   = (const float*)d_in[4];
    const float* Wv   = (const float*)d_in[5];
    const float* Wo   = (const float*)d_in[6];
    float* out = (float*)d_out;

    __hip_bfloat16* qh = (__hip_bfloat16*)d_ws;            // 4096 x 2560 bf16
    __hip_bfloat16* kh = qh + (size_t)ROWS * QH_COLS;      // 4096 x 640
    __hip_bfloat16* vh = kh + (size_t)ROWS * KV_COLS;      // 4096 x 640
    float* ob = (float*)(vh + (size_t)ROWS * KV_COLS);     // 4096 x 2560 fp32

    dim3 blk(256);
    sgemm_t<__hip_bfloat16><<<dim3(QH_COLS / BN, ROWS / BM), blk, 0, stream>>>(x, Wq, qh, ROWS, QH_COLS, HIDDEN);
    sgemm_t<__hip_bfloat16><<<dim3(KV_COLS / BN, ROWS / BM), blk, 0, stream>>>(x, Wk, kh, ROWS, KV_COLS, HIDDEN);
    sgemm_t<__hip_bfloat16><<<dim3(KV_COLS / BN, ROWS / BM), blk, 0, stream>>>(x, Wv, vh, ROWS, KV_COLS, HIDDEN);
    rope_bf16<<<(ROWS * (NH + NKV) * 40) / 256, blk, 0, stream>>>(qh, kh, cf, sf);
    attn_mfma<<<dim3(SEQ / 64, NH, BATCH), blk, 0, stream>>>(qh, kh, vh, ob);
    sgemm_t<float><<<dim3(HIDDEN / BN, ROWS / BM), blk, 0, stream>>>(ob, Wo, out, ROWS, HIDDEN, HIDDEN);
}

// Round 4
// 765.368 us; speedup vs baseline: 5.8882x; 3.0807x over previous
//
#include <hip/hip_runtime.h>
#include <hip/hip_bf16.h>
#include <math.h>

#define HIDDEN 2560
#define NH 32
#define NKV 8
#define HD 80
#define BATCH 2
#define SEQ 2048
#define QH_COLS (NH*HD)    // 2560
#define KV_COLS (NKV*HD)   // 640
#define ROWS (BATCH*SEQ)   // 4096

typedef __attribute__((ext_vector_type(4))) float floatx4;
typedef __attribute__((ext_vector_type(8))) short shortx8;
typedef __attribute__((ext_vector_type(4))) unsigned short u16x4;
typedef unsigned short u16;

__device__ inline u16 f2bf(float f) { __hip_bfloat16 h = __float2bfloat16(f); return *(u16*)&h; }
__device__ inline int swz(int r) { return (r + (r >> 2)) & 3; }
__device__ inline void storeC(float v, float* p) { *p = v; }
__device__ inline void storeC(float v, u16* p) { *p = f2bf(v); }

// ---------------- fp32 -> bf16 elementwise (x) ----------------
__global__ __launch_bounds__(256) void conv_bf16(const float* __restrict__ x,
                                                 u16* __restrict__ y) {
    int i = (blockIdx.x * 256 + threadIdx.x) * 4;
    float4 v = *(const float4*)(x + i);
    u16x4 o = { f2bf(v.x), f2bf(v.y), f2bf(v.z), f2bf(v.w) };
    *(u16x4*)(y + i) = o;
}

// ---------------- fp32 [K][N] -> bf16 [N][K] transpose-convert ----------------
__global__ __launch_bounds__(256) void transpose_conv(const float* __restrict__ W,
                                                      u16* __restrict__ Wt,
                                                      int K, int N) {
    __shared__ float tile[64][65];
    const int tid = threadIdx.x;
    const int n0 = blockIdx.x * 64, k0 = blockIdx.y * 64;
    const int r = tid >> 4, c4 = (tid & 15) * 4;
#pragma unroll
    for (int i = 0; i < 4; i++) {
        float4 v = *(const float4*)(W + (size_t)(k0 + r + i * 16) * N + n0 + c4);
        tile[r + i * 16][c4 + 0] = v.x;
        tile[r + i * 16][c4 + 1] = v.y;
        tile[r + i * 16][c4 + 2] = v.z;
        tile[r + i * 16][c4 + 3] = v.w;
    }
    __syncthreads();
    const int n = tid >> 2, kg = (tid & 3) * 16;
    __align__(16) u16 tmp[16];
#pragma unroll
    for (int j = 0; j < 16; j++) tmp[j] = f2bf(tile[kg + j][n]);
    u16* dst = Wt + (size_t)(n0 + n) * K + k0 + kg;
    *(uint4*)dst = *(const uint4*)tmp;
    *(uint4*)(dst + 8) = *(const uint4*)(tmp + 8);
}

// ---------------- bf16 MFMA GEMM: C[M,N] = A[M,K] @ Bt[N,K]^T ----------------
// 128x128 tile, BK=32, 4 waves in 2x2, each wave 4x4 MFMA 16x16x32.
// Staging via global_load_lds width=16 into packed [128][32] LDS with XOR
// kblock swizzle (stored s = kb ^ swz(r)) -> b128 frag reads are 2-way (free).
template <typename OutT>
__global__ __launch_bounds__(256) void gemm_mfma(const u16* __restrict__ A,
                                                 const u16* __restrict__ Bt,
                                                 OutT* __restrict__ C,
                                                 int M, int N, int K) {
    __shared__ __align__(16) u16 As[128 * 32];
    __shared__ __align__(16) u16 Bs[128 * 32];
    const int tid = threadIdx.x;
    const int wave = tid >> 6, lane = tid & 63;
    const int m16 = lane & 15, quad = lane >> 4;
    const int wr = wave >> 1, wc = wave & 1;
    const int bm = blockIdx.y * 128, bn = blockIdx.x * 128;

    // staging sources: 2 chunks each of A and B per wave (fixed across K-loop)
    const u16* gA[2]; const u16* gB[2]; u16* lA[2]; u16* lB[2];
#pragma unroll
    for (int i = 0; i < 2; i++) {
        int c = wave + i * 4;
        int o = c * 1024 + lane * 16;      // byte offset in packed tile
        int r = o >> 6;                    // tile row
        int s = (o >> 4) & 3;              // stored kblock position
        int kb = s ^ swz(r);               // global kblock loaded into s
        gA[i] = A  + (size_t)(bm + r) * K + kb * 8;
        gB[i] = Bt + (size_t)(bn + r) * K + kb * 8;
        lA[i] = As + (o >> 1);
        lB[i] = Bs + (o >> 1);
    }
    // fragment LDS offsets (fixed)
    int offA[4], offB[4];
#pragma unroll
    for (int i = 0; i < 4; i++) {
        int ra = wr * 64 + i * 16 + m16;
        offA[i] = ra * 32 + (quad ^ swz(ra)) * 8;
        int rb = wc * 64 + i * 16 + m16;
        offB[i] = rb * 32 + (quad ^ swz(rb)) * 8;
    }

    floatx4 acc[4][4];
#pragma unroll
    for (int i = 0; i < 4; i++)
#pragma unroll
        for (int j = 0; j < 4; j++) acc[i][j] = (floatx4){0.f, 0.f, 0.f, 0.f};

    for (int k0 = 0; k0 < K; k0 += 32) {
#pragma unroll
        for (int i = 0; i < 2; i++) {
            __builtin_amdgcn_global_load_lds(
                (const __attribute__((address_space(1))) unsigned int*)(gA[i] + k0),
                (__attribute__((address_space(3))) unsigned int*)lA[i], 16, 0, 0);
            __builtin_amdgcn_global_load_lds(
                (const __attribute__((address_space(1))) unsigned int*)(gB[i] + k0),
                (__attribute__((address_space(3))) unsigned int*)lB[i], 16, 0, 0);
        }
        __syncthreads();
        shortx8 af[4], bfr[4];
#pragma unroll
        for (int i = 0; i < 4; i++) af[i] = *(const shortx8*)(As + offA[i]);
#pragma unroll
        for (int j = 0; j < 4; j++) bfr[j] = *(const shortx8*)(Bs + offB[j]);
#pragma unroll
        for (int i = 0; i < 4; i++)
#pragma unroll
            for (int j = 0; j < 4; j++)
                acc[i][j] = __builtin_amdgcn_mfma_f32_16x16x32_bf16(af[i], bfr[j], acc[i][j], 0, 0, 0);
        __syncthreads();
    }
#pragma unroll
    for (int i = 0; i < 4; i++)
#pragma unroll
        for (int j = 0; j < 4; j++)
#pragma unroll
            for (int p = 0; p < 4; p++) {
                int row = bm + wr * 64 + i * 16 + quad * 4 + p;
                int col = bn + wc * 64 + j * 16 + m16;
                storeC(acc[i][j][p], &C[(size_t)row * N + col]);
            }
}

// ---------------- RoPE, in place on bf16 q/k ----------------
__global__ __launch_bounds__(256) void rope_bf16(__hip_bfloat16* __restrict__ qh,
                                                 __hip_bfloat16* __restrict__ kh,
                                                 const float* __restrict__ cf,
                                                 const float* __restrict__ sf) {
    int idx = blockIdx.x * 256 + threadIdx.x;
    int d  = idx % 40;
    int t  = idx / 40;
    int hh = t % (NH + NKV);
    int g  = t / (NH + NKV);
    int s  = g & (SEQ - 1);
    float c1 = cf[s * HD + d],      s1 = sf[s * HD + d];
    float c2 = cf[s * HD + d + 40], s2 = sf[s * HD + d + 40];
    __hip_bfloat16* p = (hh < NH) ? (qh + (size_t)g * QH_COLS + hh * HD)
                                  : (kh + (size_t)g * KV_COLS + (hh - NH) * HD);
    float x1 = __bfloat162float(p[d]);
    float x2 = __bfloat162float(p[d + 40]);
    p[d]      = __float2bfloat16(x1 * c1 - x2 * s1);
    p[d + 40] = __float2bfloat16(x2 * c2 + x1 * s2);
}

// ---------------- MFMA flash attention, async-staged (R3, bf16 out) ----------------
#define VT_S 72
#define PW_S 72

__device__ __forceinline__ void async_tile(const u16* gbase, size_t rs,
                                           u16* lds, int wave, int lane) {
    for (int c = wave; c < 10; c += 4) {
        int o = c * 1024 + lane * 16;
        int r = o / 160;
        int cb = o % 160;
        const u16* g = gbase + (size_t)r * rs + (cb >> 1);
        __builtin_amdgcn_global_load_lds(
            (const __attribute__((address_space(1))) unsigned int*)g,
            (__attribute__((address_space(3))) unsigned int*)(lds + c * 512 + lane * 8),
            16, 0, 0);
    }
}

__global__ __launch_bounds__(256) void attn_mfma(const u16* __restrict__ qg,
                                                 const u16* __restrict__ kgp,
                                                 const u16* __restrict__ vgp,
                                                 u16* __restrict__ ob) {
    __shared__ __align__(16) u16 Qs[64 * 80];
    __shared__ __align__(16) u16 Kb[2][64 * 80];
    __shared__ __align__(16) u16 Vt[80 * VT_S];
    __shared__ __align__(16) u16 Pw[4][16 * PW_S];

    const int tid  = threadIdx.x;
    const int wave = tid >> 6;
    const int lane = tid & 63;
    const int m16  = lane & 15;
    const int quad = lane >> 4;
    const int qt = blockIdx.x;
    const int h  = blockIdx.y;
    const int b  = blockIdx.z;
    const int kvh = h >> 2;
    const float scale = 0.11180339887498949f;
    const int qbase = qt * 64;

    const u16* qgb = qg + (size_t)(b * SEQ + qbase) * QH_COLS + h * HD;
    const u16* kg0 = kgp + (size_t)(b * SEQ) * KV_COLS + kvh * HD;
    const u16* vg0 = vgp + (size_t)(b * SEQ) * KV_COLS + kvh * HD;

    async_tile(qgb, QH_COLS, Qs, wave, lane);
    async_tile(kg0, KV_COLS, Kb[0], wave, lane);
    shortx8 vr[3];
    {
#pragma unroll
        for (int j = 0; j < 3; j++) {
            int c = j * 256 + tid;
            if (c < 640) {
                int dblk = c >> 6, r = c & 63;
                vr[j] = *(const shortx8*)(vg0 + (size_t)r * KV_COLS + dblk * 8);
            }
        }
    }
    __syncthreads();

#pragma unroll
    for (int j = 0; j < 3; j++) {
        int c = j * 256 + tid;
        if (c < 640) {
            int dblk = c >> 6, r = c & 63;
#pragma unroll
            for (int i = 0; i < 8; i++) Vt[(dblk * 8 + i) * VT_S + r] = vr[j][i];
        }
    }

    const shortx8 z8 = {0, 0, 0, 0, 0, 0, 0, 0};
    shortx8 qf0, qf1, qf2;
    {
        const u16* qrow = &Qs[(wave * 16 + m16) * 80];
        qf0 = *(const shortx8*)(qrow + quad * 8);
        qf1 = *(const shortx8*)(qrow + 32 + quad * 8);
        shortx8 t = *(const shortx8*)(qrow + 64 + (quad & 1) * 8);
        qf2 = (quad < 2) ? t : z8;
    }
    __syncthreads();

    floatx4 Oacc[5];
#pragma unroll
    for (int n = 0; n < 5; n++) Oacc[n] = (floatx4){0.f, 0.f, 0.f, 0.f};
    float mrow[4], lrow[4];
#pragma unroll
    for (int p = 0; p < 4; p++) { mrow[p] = -1.0e30f; lrow[p] = 0.0f; }

    for (int kt = 0; kt <= qt; kt++) {
        const int cur = kt & 1;
        const bool more = (kt < qt);
        if (more) {
            const u16* kg = kg0 + (size_t)(kt + 1) * 64 * KV_COLS;
            async_tile(kg, KV_COLS, Kb[cur ^ 1], wave, lane);
            const u16* vg = vg0 + (size_t)(kt + 1) * 64 * KV_COLS;
#pragma unroll
            for (int j = 0; j < 3; j++) {
                int c = j * 256 + tid;
                if (c < 640) {
                    int dblk = c >> 6, r = c & 63;
                    vr[j] = *(const shortx8*)(vg + (size_t)r * KV_COLS + dblk * 8);
                }
            }
        }

        const bool diag = (kt == qt);
        const int gmax = diag ? wave : 3;

        floatx4 S[4];
#pragma unroll
        for (int g = 0; g < 4; g++) {
            if (g > gmax) continue;
            const u16* krow = &Kb[cur][(g * 16 + m16) * 80];
            shortx8 kf0 = *(const shortx8*)(krow + quad * 8);
            shortx8 kf1 = *(const shortx8*)(krow + 32 + quad * 8);
            shortx8 t  = *(const shortx8*)(krow + 64 + (quad & 1) * 8);
            shortx8 kf2 = (quad < 2) ? t : z8;
            floatx4 s = (floatx4){0.f, 0.f, 0.f, 0.f};
            s = __builtin_amdgcn_mfma_f32_16x16x32_bf16(qf0, kf0, s, 0, 0, 0);
            s = __builtin_amdgcn_mfma_f32_16x16x32_bf16(qf1, kf1, s, 0, 0, 0);
            s = __builtin_amdgcn_mfma_f32_16x16x32_bf16(qf2, kf2, s, 0, 0, 0);
            S[g] = s;
        }

        float newm[4];
#pragma unroll
        for (int p = 0; p < 4; p++) newm[p] = mrow[p];
#pragma unroll
        for (int g = 0; g < 4; g++) {
            if (g > gmax) continue;
#pragma unroll
            for (int p = 0; p < 4; p++) {
                float s = S[g][p] * scale;
                if (diag && g == wave && (g * 16 + m16) > (wave * 16 + quad * 4 + p))
                    s = -1.0e30f;
                S[g][p] = s;
                newm[p] = fmaxf(newm[p], s);
            }
        }
#pragma unroll
        for (int p = 0; p < 4; p++)
#pragma unroll
            for (int o = 1; o < 16; o <<= 1)
                newm[p] = fmaxf(newm[p], __shfl_xor(newm[p], o));

        float alpha[4], rsum[4];
#pragma unroll
        for (int p = 0; p < 4; p++) {
            alpha[p] = __expf(mrow[p] - newm[p]);
            rsum[p] = 0.0f;
        }
#pragma unroll
        for (int g = 0; g < 4; g++) {
#pragma unroll
            for (int p = 0; p < 4; p++) {
                u16 pb = 0;
                if (g <= gmax) {
                    float pe = __expf(S[g][p] - newm[p]);
                    rsum[p] += pe;
                    pb = f2bf(pe);
                }
                Pw[wave][(quad * 4 + p) * PW_S + g * 16 + m16] = pb;
            }
        }
#pragma unroll
        for (int p = 0; p < 4; p++) {
#pragma unroll
            for (int o = 1; o < 16; o <<= 1)
                rsum[p] += __shfl_xor(rsum[p], o);
            lrow[p] = lrow[p] * alpha[p] + rsum[p];
            mrow[p] = newm[p];
        }
#pragma unroll
        for (int n = 0; n < 5; n++)
#pragma unroll
            for (int p = 0; p < 4; p++) Oacc[n][p] *= alpha[p];

        shortx8 pfrag[2];
#pragma unroll
        for (int f = 0; f < 2; f++)
            pfrag[f] = *(const shortx8*)(&Pw[wave][m16 * PW_S + f * 32 + quad * 8]);
#pragma unroll
        for (int n = 0; n < 5; n++) {
#pragma unroll
            for (int f = 0; f < 2; f++) {
                shortx8 vf = *(const shortx8*)(&Vt[(n * 16 + m16) * VT_S + f * 32 + quad * 8]);
                Oacc[n] = __builtin_amdgcn_mfma_f32_16x16x32_bf16(pfrag[f], vf, Oacc[n], 0, 0, 0);
            }
        }

        __syncthreads();
        if (more) {
#pragma unroll
            for (int j = 0; j < 3; j++) {
                int c = j * 256 + tid;
                if (c < 640) {
                    int dblk = c >> 6, r = c & 63;
#pragma unroll
                    for (int i = 0; i < 8; i++) Vt[(dblk * 8 + i) * VT_S + r] = vr[j][i];
                }
            }
        }
        __syncthreads();
    }

    float inv[4];
#pragma unroll
    for (int p = 0; p < 4; p++) inv[p] = 1.0f / lrow[p];
#pragma unroll
    for (int n = 0; n < 5; n++)
#pragma unroll
        for (int p = 0; p < 4; p++) {
            size_t row = (size_t)(b * SEQ + qbase + wave * 16 + quad * 4 + p);
            ob[row * QH_COLS + h * HD + n * 16 + m16] = f2bf(Oacc[n][p] * inv[p]);
        }
}

// ---------------- launch ----------------
extern "C" void kernel_launch(void* const* d_in, const int* in_sizes, int n_in,
                              void* d_out, int out_size, void* d_ws, size_t ws_size,
                              hipStream_t stream) {
    const float* x    = (const float*)d_in[0];
    const float* cf   = (const float*)d_in[1];
    const float* sf   = (const float*)d_in[2];
    const float* Wq   = (const float*)d_in[3];
    const float* Wk   = (const float*)d_in[4];
    const float* Wv   = (const float*)d_in[5];
    const float* Wo   = (const float*)d_in[6];
    float* out = (float*)d_out;

    u16* xh  = (u16*)d_ws;                             // 4096x2560; later reused as obh
    u16* Wqt = xh  + (size_t)ROWS * QH_COLS;           // 2560x2560 (Nt x K)
    u16* Wkt = Wqt + (size_t)QH_COLS * HIDDEN;         // 640x2560
    u16* Wvt = Wkt + (size_t)KV_COLS * HIDDEN;         // 640x2560
    u16* Wot = Wvt + (size_t)KV_COLS * HIDDEN;         // 2560x2560
    u16* qh  = Wot + (size_t)HIDDEN * QH_COLS;         // 4096x2560
    u16* kh  = qh  + (size_t)ROWS * QH_COLS;           // 4096x640
    u16* vh  = kh  + (size_t)ROWS * KV_COLS;           // 4096x640
    u16* obh = xh;                                     // alias: x dead after projections

    dim3 blk(256);
    conv_bf16<<<(ROWS * HIDDEN / 4) / 256, blk, 0, stream>>>(x, xh);
    transpose_conv<<<dim3(QH_COLS / 64, HIDDEN / 64), blk, 0, stream>>>(Wq, Wqt, HIDDEN, QH_COLS);
    transpose_conv<<<dim3(KV_COLS / 64, HIDDEN / 64), blk, 0, stream>>>(Wk, Wkt, HIDDEN, KV_COLS);
    transpose_conv<<<dim3(KV_COLS / 64, HIDDEN / 64), blk, 0, stream>>>(Wv, Wvt, HIDDEN, KV_COLS);
    transpose_conv<<<dim3(HIDDEN / 64, QH_COLS / 64), blk, 0, stream>>>(Wo, Wot, QH_COLS, HIDDEN);

    gemm_mfma<u16><<<dim3(QH_COLS / 128, ROWS / 128), blk, 0, stream>>>(xh, Wqt, qh, ROWS, QH_COLS, HIDDEN);
    gemm_mfma<u16><<<dim3(KV_COLS / 128, ROWS / 128), blk, 0, stream>>>(xh, Wkt, kh, ROWS, KV_COLS, HIDDEN);
    gemm_mfma<u16><<<dim3(KV_COLS / 128, ROWS / 128), blk, 0, stream>>>(xh, Wvt, vh, ROWS, KV_COLS, HIDDEN);

    rope_bf16<<<(ROWS * (NH + NKV) * 40) / 256, blk, 0, stream>>>((__hip_bfloat16*)qh, (__hip_bfloat16*)kh, cf, sf);
    attn_mfma<<<dim3(SEQ / 64, NH, BATCH), blk, 0, stream>>>(qh, kh, vh, obh);

    gemm_mfma<float><<<dim3(HIDDEN / 128, ROWS / 128), blk, 0, stream>>>(obh, Wot, out, ROWS, HIDDEN, QH_COLS);
}

// Round 5
// 665.241 us; speedup vs baseline: 6.7744x; 1.1505x over previous
//
#include <hip/hip_runtime.h>
#include <hip/hip_bf16.h>
#include <math.h>

#define HIDDEN 2560
#define NH 32
#define NKV 8
#define HD 80
#define BATCH 2
#define SEQ 2048
#define QH_COLS (NH*HD)    // 2560
#define KV_COLS (NKV*HD)   // 640
#define ROWS (BATCH*SEQ)   // 4096

typedef __attribute__((ext_vector_type(4))) float floatx4;
typedef __attribute__((ext_vector_type(8))) short shortx8;
typedef __attribute__((ext_vector_type(4))) unsigned short u16x4;
typedef unsigned short u16;

__device__ inline u16 f2bf(float f) { __hip_bfloat16 h = __float2bfloat16(f); return *(u16*)&h; }
__device__ inline int swz(int r) { return (r + (r >> 2)) & 3; }
__device__ inline void storeC(float v, float* p) { *p = v; }
__device__ inline void storeC(float v, u16* p) { *p = f2bf(v); }

#if __has_builtin(__builtin_amdgcn_exp2f)
__device__ inline float fexp2(float x) { return __builtin_amdgcn_exp2f(x); }
#else
__device__ inline float fexp2(float x) { return __expf(x * 0.6931471805599453f); }
#endif

// ---------------- fp32 -> bf16 elementwise (x) ----------------
__global__ __launch_bounds__(256) void conv_bf16(const float* __restrict__ x,
                                                 u16* __restrict__ y) {
    int i = (blockIdx.x * 256 + threadIdx.x) * 4;
    float4 v = *(const float4*)(x + i);
    u16x4 o = { f2bf(v.x), f2bf(v.y), f2bf(v.z), f2bf(v.w) };
    *(u16x4*)(y + i) = o;
}

// ---------------- fp32 [K][N] -> bf16 [N][K] transpose-convert ----------------
__global__ __launch_bounds__(256) void transpose_conv(const float* __restrict__ W,
                                                      u16* __restrict__ Wt,
                                                      int K, int N) {
    __shared__ float tile[64][65];
    const int tid = threadIdx.x;
    const int n0 = blockIdx.x * 64, k0 = blockIdx.y * 64;
    const int r = tid >> 4, c4 = (tid & 15) * 4;
#pragma unroll
    for (int i = 0; i < 4; i++) {
        float4 v = *(const float4*)(W + (size_t)(k0 + r + i * 16) * N + n0 + c4);
        tile[r + i * 16][c4 + 0] = v.x;
        tile[r + i * 16][c4 + 1] = v.y;
        tile[r + i * 16][c4 + 2] = v.z;
        tile[r + i * 16][c4 + 3] = v.w;
    }
    __syncthreads();
    const int n = tid >> 2, kg = (tid & 3) * 16;
    __align__(16) u16 tmp[16];
#pragma unroll
    for (int j = 0; j < 16; j++) tmp[j] = f2bf(tile[kg + j][n]);
    u16* dst = Wt + (size_t)(n0 + n) * K + k0 + kg;
    *(uint4*)dst = *(const uint4*)tmp;
    *(uint4*)(dst + 8) = *(const uint4*)(tmp + 8);
}

// ---------------- bf16 MFMA GEMM: C[M,N] = A[M,K] @ Bt[N,K]^T ----------------
template <typename OutT>
__global__ __launch_bounds__(256) void gemm_mfma(const u16* __restrict__ A,
                                                 const u16* __restrict__ Bt,
                                                 OutT* __restrict__ C,
                                                 int M, int N, int K) {
    __shared__ __align__(16) u16 As[128 * 32];
    __shared__ __align__(16) u16 Bs[128 * 32];
    const int tid = threadIdx.x;
    const int wave = tid >> 6, lane = tid & 63;
    const int m16 = lane & 15, quad = lane >> 4;
    const int wr = wave >> 1, wc = wave & 1;
    const int bm = blockIdx.y * 128, bn = blockIdx.x * 128;

    const u16* gA[2]; const u16* gB[2]; u16* lA[2]; u16* lB[2];
#pragma unroll
    for (int i = 0; i < 2; i++) {
        int c = wave + i * 4;
        int o = c * 1024 + lane * 16;
        int r = o >> 6;
        int s = (o >> 4) & 3;
        int kb = s ^ swz(r);
        gA[i] = A  + (size_t)(bm + r) * K + kb * 8;
        gB[i] = Bt + (size_t)(bn + r) * K + kb * 8;
        lA[i] = As + (o >> 1);
        lB[i] = Bs + (o >> 1);
    }
    int offA[4], offB[4];
#pragma unroll
    for (int i = 0; i < 4; i++) {
        int ra = wr * 64 + i * 16 + m16;
        offA[i] = ra * 32 + (quad ^ swz(ra)) * 8;
        int rb = wc * 64 + i * 16 + m16;
        offB[i] = rb * 32 + (quad ^ swz(rb)) * 8;
    }

    floatx4 acc[4][4];
#pragma unroll
    for (int i = 0; i < 4; i++)
#pragma unroll
        for (int j = 0; j < 4; j++) acc[i][j] = (floatx4){0.f, 0.f, 0.f, 0.f};

    for (int k0 = 0; k0 < K; k0 += 32) {
#pragma unroll
        for (int i = 0; i < 2; i++) {
            __builtin_amdgcn_global_load_lds(
                (const __attribute__((address_space(1))) unsigned int*)(gA[i] + k0),
                (__attribute__((address_space(3))) unsigned int*)lA[i], 16, 0, 0);
            __builtin_amdgcn_global_load_lds(
                (const __attribute__((address_space(1))) unsigned int*)(gB[i] + k0),
                (__attribute__((address_space(3))) unsigned int*)lB[i], 16, 0, 0);
        }
        __syncthreads();
        shortx8 af[4], bfr[4];
#pragma unroll
        for (int i = 0; i < 4; i++) af[i] = *(const shortx8*)(As + offA[i]);
#pragma unroll
        for (int j = 0; j < 4; j++) bfr[j] = *(const shortx8*)(Bs + offB[j]);
#pragma unroll
        for (int i = 0; i < 4; i++)
#pragma unroll
            for (int j = 0; j < 4; j++)
                acc[i][j] = __builtin_amdgcn_mfma_f32_16x16x32_bf16(af[i], bfr[j], acc[i][j], 0, 0, 0);
        __syncthreads();
    }
#pragma unroll
    for (int i = 0; i < 4; i++)
#pragma unroll
        for (int j = 0; j < 4; j++)
#pragma unroll
            for (int p = 0; p < 4; p++) {
                int row = bm + wr * 64 + i * 16 + quad * 4 + p;
                int col = bn + wc * 64 + j * 16 + m16;
                storeC(acc[i][j][p], &C[(size_t)row * N + col]);
            }
}

// ---------------- RoPE, in place on bf16 q/k; Q pre-scaled by scale*log2(e) ----------------
__global__ __launch_bounds__(256) void rope_bf16(__hip_bfloat16* __restrict__ qh,
                                                 __hip_bfloat16* __restrict__ kh,
                                                 const float* __restrict__ cf,
                                                 const float* __restrict__ sf) {
    int idx = blockIdx.x * 256 + threadIdx.x;
    int d  = idx % 40;
    int t  = idx / 40;
    int hh = t % (NH + NKV);
    int g  = t / (NH + NKV);
    int s  = g & (SEQ - 1);
    float c1 = cf[s * HD + d],      s1 = sf[s * HD + d];
    float c2 = cf[s * HD + d + 40], s2 = sf[s * HD + d + 40];
    const float qsc = (hh < NH) ? (float)(0.11180339887498949 * 1.4426950408889634) : 1.0f;
    __hip_bfloat16* p = (hh < NH) ? (qh + (size_t)g * QH_COLS + hh * HD)
                                  : (kh + (size_t)g * KV_COLS + (hh - NH) * HD);
    float x1 = __bfloat162float(p[d]);
    float x2 = __bfloat162float(p[d + 40]);
    p[d]      = __float2bfloat16((x1 * c1 - x2 * s1) * qsc);
    p[d + 40] = __float2bfloat16((x2 * c2 + x1 * s2) * qsc);
}

// ---------------- MFMA flash attention, S^T formulation ----------------
// grid (SEQ/64, NH, BATCH) with qt = 31 - blockIdx.x (LPT). Block 256 = 4 waves;
// wave w owns Q rows w*16..w*16+15. Computes S^T = K·Q^T (keys=M, queries=N):
// each lane then holds 16 scores of ONE query (q = lane&15) -> softmax reduce is
// in-lane + 2 shuffles; alpha/l are lane scalars. PV as O^T = V^T·P.
// LDS: Ks 10.25K + Vt 11.25K + QP(Q staging, reused as P) 10.25K = 31.75 KB.
#define VT_S 72
#define PW_S 72

__device__ __forceinline__ void async_tile(const u16* gbase, size_t rs,
                                           u16* lds, int wave, int lane) {
    for (int c = wave; c < 10; c += 4) {
        int o = c * 1024 + lane * 16;
        int r = o / 160;
        int cb = o % 160;
        const u16* g = gbase + (size_t)r * rs + (cb >> 1);
        __builtin_amdgcn_global_load_lds(
            (const __attribute__((address_space(1))) unsigned int*)g,
            (__attribute__((address_space(3))) unsigned int*)(lds + c * 512 + lane * 8),
            16, 0, 0);
    }
}

__global__ __launch_bounds__(256, 4) void attn_mfma(const u16* __restrict__ qg,
                                                    const u16* __restrict__ kgp,
                                                    const u16* __restrict__ vgp,
                                                    u16* __restrict__ ob) {
    __shared__ __align__(16) u16 QP[64 * 80];   // Q staging; after prologue: per-wave P
    __shared__ __align__(16) u16 Ks[64 * 80];   // [key][d], packed 160B rows
    __shared__ __align__(16) u16 Vt[80 * VT_S]; // [d][key]

    const int tid  = threadIdx.x;
    const int wave = tid >> 6;
    const int lane = tid & 63;
    const int m16  = lane & 15;
    const int quad = lane >> 4;
    const int qt = (int)gridDim.x - 1 - (int)blockIdx.x;   // LPT: long blocks first
    const int h  = blockIdx.y;
    const int b  = blockIdx.z;
    const int kvh = h >> 2;
    const int qbase = qt * 64;

    const u16* qgb = qg + (size_t)(b * SEQ + qbase) * QH_COLS + h * HD;
    const u16* kg0 = kgp + (size_t)(b * SEQ) * KV_COLS + kvh * HD;
    const u16* vg0 = vgp + (size_t)(b * SEQ) * KV_COLS + kvh * HD;
    u16* Pq = QP + wave * 16 * PW_S;   // per-wave P[query][key], 16 x 64 used

    // ---- prologue: async-stage Q; reg-load K0,V0 ----
    async_tile(qgb, QH_COLS, QP, wave, lane);
    shortx8 kr[3], vr[3];
#pragma unroll
    for (int j = 0; j < 3; j++) {
        int c = j * 256 + tid;
        if (c < 640) {
            int dblk = c >> 6, r = c & 63;
            kr[j] = *(const shortx8*)(kg0 + (size_t)r * KV_COLS + dblk * 8);
            vr[j] = *(const shortx8*)(vg0 + (size_t)r * KV_COLS + dblk * 8);
        }
    }
    __syncthreads();    // Q in LDS; kr/vr arrived

    // write K0 (b128) and V0 (transposed) to LDS; read Q frags
#pragma unroll
    for (int j = 0; j < 3; j++) {
        int c = j * 256 + tid;
        if (c < 640) {
            int dblk = c >> 6, r = c & 63;
            *(shortx8*)(Ks + r * 80 + dblk * 8) = kr[j];
#pragma unroll
            for (int i = 0; i < 8; i++) Vt[(dblk * 8 + i) * VT_S + r] = vr[j][i];
        }
    }
    const shortx8 z8 = {0, 0, 0, 0, 0, 0, 0, 0};
    shortx8 qf0, qf1, qf2;
    {
        const u16* qrow = &QP[(wave * 16 + m16) * 80];
        qf0 = *(const shortx8*)(qrow + quad * 8);
        qf1 = *(const shortx8*)(qrow + 32 + quad * 8);
        shortx8 t = *(const shortx8*)(qrow + 64 + (quad & 1) * 8);
        qf2 = (quad < 2) ? t : z8;
    }
    __syncthreads();    // Ks/Vt ready; QP free for P

    floatx4 Oacc[5];
#pragma unroll
    for (int n = 0; n < 5; n++) Oacc[n] = (floatx4){0.f, 0.f, 0.f, 0.f};
    float mrow = -1.0e30f, lrow = 0.0f;   // per-lane: query q = m16 (log2 domain)

    for (int kt = 0; kt <= qt; kt++) {
        const bool more = (kt < qt);
        if (more) {   // prefetch kt+1 into regs (drained by post-compute barrier)
            const u16* kg = kg0 + (size_t)(kt + 1) * 64 * KV_COLS;
            const u16* vg = vg0 + (size_t)(kt + 1) * 64 * KV_COLS;
#pragma unroll
            for (int j = 0; j < 3; j++) {
                int c = j * 256 + tid;
                if (c < 640) {
                    int dblk = c >> 6, r = c & 63;
                    kr[j] = *(const shortx8*)(kg + (size_t)r * KV_COLS + dblk * 8);
                    vr[j] = *(const shortx8*)(vg + (size_t)r * KV_COLS + dblk * 8);
                }
            }
        }

        const bool diag = (kt == qt);
        const int gmax = diag ? wave : 3;   // key groups beyond the diagonal: skip

        // S^T = K·Q^T : A = K rows (keys), B = Q^T. D col = query = m16,
        // D row = key = g*16 + quad*4 + p.
        floatx4 S[4];
#pragma unroll
        for (int g = 0; g < 4; g++) {
            if (g > gmax) continue;
            const u16* krow = &Ks[(g * 16 + m16) * 80];
            shortx8 kf0 = *(const shortx8*)(krow + quad * 8);
            shortx8 kf1 = *(const shortx8*)(krow + 32 + quad * 8);
            shortx8 t  = *(const shortx8*)(krow + 64 + (quad & 1) * 8);
            shortx8 kf2 = (quad < 2) ? t : z8;
            floatx4 s = (floatx4){0.f, 0.f, 0.f, 0.f};
            s = __builtin_amdgcn_mfma_f32_16x16x32_bf16(kf0, qf0, s, 0, 0, 0);
            s = __builtin_amdgcn_mfma_f32_16x16x32_bf16(kf1, qf1, s, 0, 0, 0);
            s = __builtin_amdgcn_mfma_f32_16x16x32_bf16(kf2, qf2, s, 0, 0, 0);
            S[g] = s;
        }

        // mask + in-lane max over this lane's 16 scores, then 2-shuffle reduce
        float mx = mrow;
#pragma unroll
        for (int g = 0; g < 4; g++) {
            if (g > gmax) continue;
#pragma unroll
            for (int p = 0; p < 4; p++) {
                float s = S[g][p];
                if (diag && g == wave && (quad * 4 + p) > m16) s = -1.0e30f;
                S[g][p] = s;
                mx = fmaxf(mx, s);
            }
        }
        mx = fmaxf(mx, __shfl_xor(mx, 16));
        mx = fmaxf(mx, __shfl_xor(mx, 32));

        float alpha = fexp2(mrow - mx);
        float rsum = 0.0f;
#pragma unroll
        for (int g = 0; g < 4; g++) {
#pragma unroll
            for (int p = 0; p < 4; p++) {
                u16 pb = 0;
                if (g <= gmax) {
                    float pe = fexp2(S[g][p] - mx);
                    rsum += pe;
                    pb = f2bf(pe);
                }
                Pq[m16 * PW_S + g * 16 + quad * 4 + p] = pb;
            }
        }
        rsum += __shfl_xor(rsum, 16);
        rsum += __shfl_xor(rsum, 32);
        lrow = lrow * alpha + rsum;
        mrow = mx;
#pragma unroll
        for (int n = 0; n < 5; n++) Oacc[n] *= alpha;

        // O^T += V^T·P : A = V^T (d x key) from Vt, B = P (key x query) from Pq.
        // Wave-local LDS roundtrip: compiler's lgkm wait covers write->read.
        shortx8 pf[2];
#pragma unroll
        for (int f = 0; f < 2; f++)
            pf[f] = *(const shortx8*)(Pq + m16 * PW_S + f * 32 + quad * 8);
#pragma unroll
        for (int n = 0; n < 5; n++) {
#pragma unroll
            for (int f = 0; f < 2; f++) {
                shortx8 vf = *(const shortx8*)(&Vt[(n * 16 + m16) * VT_S + f * 32 + quad * 8]);
                Oacc[n] = __builtin_amdgcn_mfma_f32_16x16x32_bf16(vf, pf[f], Oacc[n], 0, 0, 0);
            }
        }

        __syncthreads();   // all waves done reading Ks/Vt; drains kr/vr vmcnt
        if (more) {
#pragma unroll
            for (int j = 0; j < 3; j++) {
                int c = j * 256 + tid;
                if (c < 640) {
                    int dblk = c >> 6, r = c & 63;
                    *(shortx8*)(Ks + r * 80 + dblk * 8) = kr[j];
#pragma unroll
                    for (int i = 0; i < 8; i++) Vt[(dblk * 8 + i) * VT_S + r] = vr[j][i];
                }
            }
        }
        __syncthreads();
    }

    // epilogue: O[row q][col d] = Oacc^T / l ; 4 consecutive d per (n) -> 8B stores
    const float invl = 1.0f / lrow;
    const size_t row = (size_t)(b * SEQ + qbase + wave * 16 + m16);
#pragma unroll
    for (int n = 0; n < 5; n++) {
        u16x4 o4 = { f2bf(Oacc[n][0] * invl), f2bf(Oacc[n][1] * invl),
                     f2bf(Oacc[n][2] * invl), f2bf(Oacc[n][3] * invl) };
        *(u16x4*)(ob + row * QH_COLS + h * HD + n * 16 + quad * 4) = o4;
    }
}

// ---------------- launch ----------------
extern "C" void kernel_launch(void* const* d_in, const int* in_sizes, int n_in,
                              void* d_out, int out_size, void* d_ws, size_t ws_size,
                              hipStream_t stream) {
    const float* x    = (const float*)d_in[0];
    const float* cf   = (const float*)d_in[1];
    const float* sf   = (const float*)d_in[2];
    const float* Wq   = (const float*)d_in[3];
    const float* Wk   = (const float*)d_in[4];
    const float* Wv   = (const float*)d_in[5];
    const float* Wo   = (const float*)d_in[6];
    float* out = (float*)d_out;

    u16* xh  = (u16*)d_ws;                             // 4096x2560; later reused as obh
    u16* Wqt = xh  + (size_t)ROWS * QH_COLS;           // 2560x2560 (Nt x K)
    u16* Wkt = Wqt + (size_t)QH_COLS * HIDDEN;         // 640x2560
    u16* Wvt = Wkt + (size_t)KV_COLS * HIDDEN;         // 640x2560
    u16* Wot = Wvt + (size_t)KV_COLS * HIDDEN;         // 2560x2560
    u16* qh  = Wot + (size_t)HIDDEN * QH_COLS;         // 4096x2560
    u16* kh  = qh  + (size_t)ROWS * QH_COLS;           // 4096x640
    u16* vh  = kh  + (size_t)ROWS * KV_COLS;           // 4096x640
    u16* obh = xh;                                     // alias: x dead after projections

    dim3 blk(256);
    conv_bf16<<<(ROWS * HIDDEN / 4) / 256, blk, 0, stream>>>(x, xh);
    transpose_conv<<<dim3(QH_COLS / 64, HIDDEN / 64), blk, 0, stream>>>(Wq, Wqt, HIDDEN, QH_COLS);
    transpose_conv<<<dim3(KV_COLS / 64, HIDDEN / 64), blk, 0, stream>>>(Wk, Wkt, HIDDEN, KV_COLS);
    transpose_conv<<<dim3(KV_COLS / 64, HIDDEN / 64), blk, 0, stream>>>(Wv, Wvt, HIDDEN, KV_COLS);
    transpose_conv<<<dim3(HIDDEN / 64, QH_COLS / 64), blk, 0, stream>>>(Wo, Wot, QH_COLS, HIDDEN);

    gemm_mfma<u16><<<dim3(QH_COLS / 128, ROWS / 128), blk, 0, stream>>>(xh, Wqt, qh, ROWS, QH_COLS, HIDDEN);
    gemm_mfma<u16><<<dim3(KV_COLS / 128, ROWS / 128), blk, 0, stream>>>(xh, Wkt, kh, ROWS, KV_COLS, HIDDEN);
    gemm_mfma<u16><<<dim3(KV_COLS / 128, ROWS / 128), blk, 0, stream>>>(xh, Wvt, vh, ROWS, KV_COLS, HIDDEN);

    rope_bf16<<<(ROWS * (NH + NKV) * 40) / 256, blk, 0, stream>>>((__hip_bfloat16*)qh, (__hip_bfloat16*)kh, cf, sf);
    attn_mfma<<<dim3(SEQ / 64, NH, BATCH), blk, 0, stream>>>(qh, kh, vh, obh);

    gemm_mfma<float><<<dim3(HIDDEN / 128, ROWS / 128), blk, 0, stream>>>(obh, Wot, out, ROWS, HIDDEN, QH_COLS);
}